// Round 1
// baseline (1128.238 us; speedup 1.0000x reference)
//
#include <hip/hip_runtime.h>
#include <hip/hip_bf16.h>

#define NN 50000
#define NE 600000
#define NP 500000
#define DH 128
#define NRBF 16
#define NL 3

typedef __attribute__((ext_vector_type(8))) short bf16x8;
typedef __attribute__((ext_vector_type(4))) float f32x4;

__device__ __forceinline__ unsigned short f2b(float f){
  unsigned int u = __float_as_uint(f);
  u += 0x7fffu + ((u >> 16) & 1u);
  return (unsigned short)(u >> 16);
}

__device__ __forceinline__ void zero_acc(f32x4 (&acc)[4][2]){
#pragma unroll
  for (int i=0;i<4;i++)
#pragma unroll
    for (int j=0;j<2;j++)
#pragma unroll
      for (int r=0;r<4;r++) acc[i][j][r]=0.f;
}

// wave computes a 64x32 slice of a 64x128 output tile.
// X: LDS, row-major [64][stride] bf16 (stride*2 bytes multiple of 16, stride/8 odd for bank spread)
// Bp: packed weights, layout [ct(8)][kb(KB)][lane(64)][e(8)] bf16
__device__ __forceinline__ void gemm_tile(const short* X, int stride,
                                          const short* __restrict__ Bp,
                                          int KB, int t, f32x4 (&acc)[4][2]){
  const int lane = t & 63;
  const int w = t >> 6;
  const int m = lane & 15, g = lane >> 4;
  for (int kb=0; kb<KB; kb++){
    bf16x8 a[4];
#pragma unroll
    for (int rt=0; rt<4; rt++)
      a[rt] = *reinterpret_cast<const bf16x8*>(X + (rt*16+m)*stride + kb*32 + g*8);
#pragma unroll
    for (int c=0;c<2;c++){
      int ct = w*2+c;
      bf16x8 b = *reinterpret_cast<const bf16x8*>(Bp + ((size_t)(ct*KB+kb)*64 + lane)*8);
#pragma unroll
      for (int rt=0; rt<4; rt++)
        acc[rt][c] = __builtin_amdgcn_mfma_f32_16x16x32_bf16(a[rt], b, acc[rt][c], 0,0,0);
    }
  }
}

// Pack W (Kr x 128 row-major fp32, zero-padded to KB*32 rows) into B-fragment layout.
__global__ void pack_w_kernel(const float* __restrict__ W, int Kr, int KB, short* __restrict__ out){
  int idx = blockIdx.x*256 + threadIdx.x;
  int total = 8*KB*64;
  if (idx >= total) return;
  int lane = idx & 63;
  int kb = (idx>>6) % KB;
  int ct = (idx>>6) / KB;
  int col = ct*16 + (lane&15);
  int k0 = kb*32 + 8*(lane>>4);
  bf16x8 pv;
#pragma unroll
  for (int e=0;e<8;e++){
    int k = k0+e;
    float f = (k<Kr) ? W[(size_t)k*DH + col] : 0.f;
    pv[e] = (short)f2b(f);
  }
  *reinterpret_cast<bf16x8*>(out + (size_t)idx*8) = pv;
}

__global__ void rbf_kernel(const float* __restrict__ coords, const int* __restrict__ srcI,
                           const int* __restrict__ dstI, short* __restrict__ rbfp){
  int e = blockIdx.x*256 + threadIdx.x;
  if (e >= NE) return;
  int s = srcI[e], d = dstI[e];
  float dx = coords[2*s]-coords[2*d];
  float dy = coords[2*s+1]-coords[2*d+1];
  float r = sqrtf(dx*dx + dy*dy + 1e-8f);
  bf16x8 v0, v1;
#pragma unroll
  for (int i=0;i<8;i++){
    float t0 = (r - 0.1f*i)*10.f;
    v0[i] = (short)f2b(expf(-t0*t0));
    float t1 = (r - 0.1f*(i+8))*10.f;
    v1[i] = (short)f2b(expf(-t1*t1));
  }
  *reinterpret_cast<bf16x8*>(rbfp + (size_t)e*NRBF) = v0;
  *reinterpret_cast<bf16x8*>(rbfp + (size_t)e*NRBF + 8) = v1;
}

// Node MLP: y1 = relu(coords@W1+b1) computed scalar (K=2), then 128x128 GEMM via MFMA.
__global__ __launch_bounds__(256, 2) void node_kernel(
    const float* __restrict__ coords, const float* __restrict__ W1, const float* __restrict__ b1,
    const short* __restrict__ W2p, const float* __restrict__ b2,
    float* __restrict__ h, short* __restrict__ hbf)
{
  __shared__ __align__(16) short X[64*136];
  const int t = threadIdx.x;
  const int n0 = blockIdx.x*64;
  {
    int row = t >> 2;
    int n = n0 + row;
    float c0=0.f, c1=0.f;
    if (n < NN){ c0 = coords[2*n]; c1 = coords[2*n+1]; }
#pragma unroll
    for (int i=0;i<32;i++){
      int col = (t&3)*32 + i;
      float y = fmaxf(c0*W1[col] + c1*W1[DH+col] + b1[col], 0.f);
      X[row*136 + col] = (short)f2b(y);
    }
  }
  __syncthreads();
  f32x4 acc[4][2]; zero_acc(acc);
  gemm_tile(X, 136, W2p, 4, t, acc);
  const int lane=t&63, w=t>>6, m=lane&15, g=lane>>4;
  float b2v0=b2[w*32+m], b2v1=b2[w*32+16+m];
#pragma unroll
  for (int rt=0;rt<4;rt++){
#pragma unroll
    for (int c=0;c<2;c++){
      float bb = c? b2v1 : b2v0;
      int col = (w*2+c)*16 + m;
#pragma unroll
      for (int r=0;r<4;r++){
        int row = rt*16 + g*4 + r;
        int n = n0 + row;
        if (n < NN){
          float val = acc[rt][c][r] + bb;
          h[(size_t)n*DH + col] = val;
          hbf[(size_t)n*DH + col] = (short)f2b(val);
        }
      }
    }
  }
}

// Message MLP over 64-edge tile + atomic segment-sum into agg.
__global__ __launch_bounds__(256, 2) void msg_kernel(
    const short* __restrict__ hbf, const short* __restrict__ rbfp,
    const int* __restrict__ srcI, const int* __restrict__ dstI,
    const short* __restrict__ W1p, const float* __restrict__ b1,
    const short* __restrict__ W2p, const float* __restrict__ b2,
    float* __restrict__ agg)
{
  __shared__ __align__(16) short X[64*296];
  __shared__ __align__(16) short Y[64*136];
  __shared__ int srcl[64];
  __shared__ int dstl[64];
  const int t = threadIdx.x;
  const int e0 = blockIdx.x*64;

  if (t < 64) srcl[t] = srcI[e0+t];
  else if (t < 128) dstl[t-64] = dstI[e0+t-64];
  __syncthreads();

#pragma unroll
  for (int j=0;j<8;j++){
    int slot = j*256 + t;
    int lane16 = slot & 15;
    int rowhalf = slot >> 4;
    int row = rowhalf >> 1;
    int half = rowhalf & 1;
    int id = half ? dstl[row] : srcl[row];
    bf16x8 v = *reinterpret_cast<const bf16x8*>(hbf + (size_t)id*DH + lane16*8);
    *reinterpret_cast<bf16x8*>(&X[row*296 + half*DH + lane16*8]) = v;
  }
  {
    int row = t >> 2, l4 = t & 3;
    if (l4 < 2){
      bf16x8 v = *reinterpret_cast<const bf16x8*>(rbfp + (size_t)(e0+row)*NRBF + l4*8);
      *reinterpret_cast<bf16x8*>(&X[row*296 + 2*DH + l4*8]) = v;
    } else {
      bf16x8 z;
#pragma unroll
      for (int e=0;e<8;e++) z[e]=0;
      *reinterpret_cast<bf16x8*>(&X[row*296 + 2*DH + 16 + (l4-2)*8]) = z;
    }
  }
  __syncthreads();

  f32x4 acc[4][2]; zero_acc(acc);
  gemm_tile(X, 296, W1p, 9, t, acc);

  const int lane=t&63, w=t>>6, m=lane&15, g=lane>>4;
  float b1v0=b1[w*32+m], b1v1=b1[w*32+16+m];
#pragma unroll
  for (int rt=0;rt<4;rt++){
#pragma unroll
    for (int c=0;c<2;c++){
      float bb = c? b1v1 : b1v0;
#pragma unroll
      for (int r=0;r<4;r++){
        float y = fmaxf(acc[rt][c][r] + bb, 0.f);
        Y[(rt*16+g*4+r)*136 + (w*2+c)*16 + m] = (short)f2b(y);
      }
    }
  }
  __syncthreads();

  f32x4 acc2[4][2]; zero_acc(acc2);
  gemm_tile(Y, 136, W2p, 4, t, acc2);

  float b2v0=b2[w*32+m], b2v1=b2[w*32+16+m];
#pragma unroll
  for (int rt=0;rt<4;rt++){
#pragma unroll
    for (int c=0;c<2;c++){
      float bb = c? b2v1 : b2v0;
      int col = (w*2+c)*16 + m;
#pragma unroll
      for (int r=0;r<4;r++){
        int row = rt*16 + g*4 + r;
        atomicAdd(agg + (size_t)dstl[row]*DH + col, acc2[rt][c][r] + bb);
      }
    }
  }
}

// Update MLP: u_in=[h, agg] (K=256), residual add, writes fp32 h and bf16 copy in place.
__global__ __launch_bounds__(256, 2) void upd_kernel(
    const short* __restrict__ hbfin, const float* __restrict__ agg,
    const short* __restrict__ W1p, const float* __restrict__ b1,
    const short* __restrict__ W2p, const float* __restrict__ b2,
    float* __restrict__ h, short* __restrict__ hbfout)
{
  __shared__ __align__(16) short X[64*264];
  __shared__ __align__(16) short Y[64*136];
  const int t = threadIdx.x;
  const int n0 = blockIdx.x*64;
#pragma unroll
  for (int j=0;j<4;j++){
    int slot = j*256 + t;
    int lane16 = slot & 15, row = slot >> 4;
    int n = n0 + row;
    int nc = n < NN ? n : NN-1;
    bf16x8 v = *reinterpret_cast<const bf16x8*>(hbfin + (size_t)nc*DH + lane16*8);
    *reinterpret_cast<bf16x8*>(&X[row*264 + lane16*8]) = v;
    const float* ap = agg + (size_t)nc*DH + lane16*8;
    bf16x8 o;
#pragma unroll
    for (int e=0;e<8;e++) o[e] = (short)f2b(ap[e]);
    *reinterpret_cast<bf16x8*>(&X[row*264 + DH + lane16*8]) = o;
  }
  __syncthreads();

  f32x4 acc[4][2]; zero_acc(acc);
  gemm_tile(X, 264, W1p, 8, t, acc);

  const int lane=t&63, w=t>>6, m=lane&15, g=lane>>4;
  float b1v0=b1[w*32+m], b1v1=b1[w*32+16+m];
#pragma unroll
  for (int rt=0;rt<4;rt++){
#pragma unroll
    for (int c=0;c<2;c++){
      float bb = c? b1v1 : b1v0;
#pragma unroll
      for (int r=0;r<4;r++){
        float y = fmaxf(acc[rt][c][r] + bb, 0.f);
        Y[(rt*16+g*4+r)*136 + (w*2+c)*16 + m] = (short)f2b(y);
      }
    }
  }
  __syncthreads();

  f32x4 acc2[4][2]; zero_acc(acc2);
  gemm_tile(Y, 136, W2p, 4, t, acc2);

  float b2v0=b2[w*32+m], b2v1=b2[w*32+16+m];
#pragma unroll
  for (int rt=0;rt<4;rt++){
#pragma unroll
    for (int c=0;c<2;c++){
      float bb = c? b2v1 : b2v0;
      int col = (w*2+c)*16 + m;
#pragma unroll
      for (int r=0;r<4;r++){
        int row = rt*16 + g*4 + r;
        int n = n0 + row;
        if (n < NN){
          float val = h[(size_t)n*DH + col] + acc2[rt][c][r] + bb;
          h[(size_t)n*DH + col] = val;
          hbfout[(size_t)n*DH + col] = (short)f2b(val);
        }
      }
    }
  }
}

// Head: edge_in=[h[u], h[v], rc] (K=288 padded), GEMM1 + fused 128->1 dot via shuffle reduce.
__global__ __launch_bounds__(256, 2) void head_kernel(
    const short* __restrict__ hbf, const float* __restrict__ coords,
    const int* __restrict__ pairs,
    const short* __restrict__ W1p, const float* __restrict__ b1,
    const float* __restrict__ W2, const float* __restrict__ b2,
    float* __restrict__ out)
{
  __shared__ __align__(16) short X[64*296];
  __shared__ int ul[64], vl[64];
  __shared__ float lacc[64];
  const int t = threadIdx.x;
  const long p0 = (long)blockIdx.x*64;
  if (t < 64){
    long p = p0 + t;
    int u=0, v=0;
    if (p < NP){ u = pairs[2*p]; v = pairs[2*p+1]; }
    ul[t]=u; vl[t]=v; lacc[t]=0.f;
    float dx = coords[2*u]-coords[2*v], dy = coords[2*u+1]-coords[2*v+1];
    float rc = sqrtf(dx*dx + dy*dy + 1e-8f);
    X[t*296 + 256] = (short)f2b(rc);
#pragma unroll
    for (int c=257;c<288;c++) X[t*296 + c] = 0;
  }
  __syncthreads();
#pragma unroll
  for (int j=0;j<8;j++){
    int slot = j*256 + t;
    int lane16 = slot & 15;
    int rowhalf = slot >> 4;
    int row = rowhalf >> 1;
    int half = rowhalf & 1;
    int id = half ? vl[row] : ul[row];
    bf16x8 v = *reinterpret_cast<const bf16x8*>(hbf + (size_t)id*DH + lane16*8);
    *reinterpret_cast<bf16x8*>(&X[row*296 + half*DH + lane16*8]) = v;
  }
  __syncthreads();

  f32x4 acc[4][2]; zero_acc(acc);
  gemm_tile(X, 296, W1p, 9, t, acc);

  const int lane=t&63, w=t>>6, m=lane&15, g=lane>>4;
  float b1v0=b1[w*32+m], b1v1=b1[w*32+16+m];
  float w2v0=W2[w*32+m], w2v1=W2[w*32+16+m];
  float part[4][4];
#pragma unroll
  for (int rt=0;rt<4;rt++)
#pragma unroll
    for (int r=0;r<4;r++) part[rt][r]=0.f;
#pragma unroll
  for (int rt=0;rt<4;rt++){
#pragma unroll
    for (int c=0;c<2;c++){
      float bb = c? b1v1 : b1v0;
      float ww = c? w2v1 : w2v0;
#pragma unroll
      for (int r=0;r<4;r++){
        float y = fmaxf(acc[rt][c][r] + bb, 0.f);
        part[rt][r] += y*ww;
      }
    }
  }
#pragma unroll
  for (int off=1; off<16; off<<=1){
#pragma unroll
    for (int rt=0;rt<4;rt++)
#pragma unroll
      for (int r=0;r<4;r++)
        part[rt][r] += __shfl_xor(part[rt][r], off, 64);
  }
  if (m == 0){
#pragma unroll
    for (int rt=0;rt<4;rt++)
#pragma unroll
      for (int r=0;r<4;r++)
        atomicAdd(&lacc[rt*16 + g*4 + r], part[rt][r]);
  }
  __syncthreads();
  if (t < 64){
    long p = p0 + t;
    if (p < NP) out[p] = lacc[t] + b2[0];
  }
}

extern "C" void kernel_launch(void* const* d_in, const int* in_sizes, int n_in,
                              void* d_out, int out_size, void* d_ws, size_t ws_size,
                              hipStream_t stream)
{
  const float* coords  = (const float*)d_in[0];
  const int*   eidx    = (const int*)d_in[1];
  const int*   pairs   = (const int*)d_in[2];
  const float* node_W1 = (const float*)d_in[3];
  const float* node_b1 = (const float*)d_in[4];
  const float* node_W2 = (const float*)d_in[5];
  const float* node_b2 = (const float*)d_in[6];
  const float* msg_W1  = (const float*)d_in[7];
  const float* msg_b1  = (const float*)d_in[8];
  const float* msg_W2  = (const float*)d_in[9];
  const float* msg_b2  = (const float*)d_in[10];
  const float* upd_W1  = (const float*)d_in[11];
  const float* upd_b1  = (const float*)d_in[12];
  const float* upd_W2  = (const float*)d_in[13];
  const float* upd_b2  = (const float*)d_in[14];
  const float* head_W1 = (const float*)d_in[15];
  const float* head_b1 = (const float*)d_in[16];
  const float* head_W2 = (const float*)d_in[17];
  const float* head_b2 = (const float*)d_in[18];

  char* ws = (char*)d_ws;
  size_t off = 0;
  auto alloc = [&](size_t bytes)->void*{ void* p = ws + off; off += (bytes + 255) & ~(size_t)255; return p; };
  float* h      = (float*)alloc((size_t)NN*DH*4);
  short* hbf    = (short*)alloc((size_t)NN*DH*2);
  float* agg    = (float*)alloc((size_t)NN*DH*4);
  short* rbfp   = (short*)alloc((size_t)NE*NRBF*2);
  short* msgW1p = (short*)alloc((size_t)NL*288*DH*2);
  short* msgW2p = (short*)alloc((size_t)NL*DH*DH*2);
  short* updW1p = (short*)alloc((size_t)NL*256*DH*2);
  short* updW2p = (short*)alloc((size_t)NL*DH*DH*2);
  short* headW1p= (short*)alloc((size_t)288*DH*2);
  short* nodeW2p= (short*)alloc((size_t)DH*DH*2);

  const int* srcI = eidx;
  const int* dstI = eidx + NE;

  for (int l=0; l<NL; l++){
    pack_w_kernel<<<(8*9*64+255)/256, 256, 0, stream>>>(msg_W1 + (size_t)l*272*DH, 272, 9, msgW1p + (size_t)l*288*DH);
    pack_w_kernel<<<(8*4*64+255)/256, 256, 0, stream>>>(msg_W2 + (size_t)l*DH*DH, 128, 4, msgW2p + (size_t)l*DH*DH);
    pack_w_kernel<<<(8*8*64+255)/256, 256, 0, stream>>>(upd_W1 + (size_t)l*256*DH, 256, 8, updW1p + (size_t)l*256*DH);
    pack_w_kernel<<<(8*4*64+255)/256, 256, 0, stream>>>(upd_W2 + (size_t)l*DH*DH, 128, 4, updW2p + (size_t)l*DH*DH);
  }
  pack_w_kernel<<<(8*9*64+255)/256, 256, 0, stream>>>(head_W1, 257, 9, headW1p);
  pack_w_kernel<<<(8*4*64+255)/256, 256, 0, stream>>>(node_W2, 128, 4, nodeW2p);

  rbf_kernel<<<(NE+255)/256, 256, 0, stream>>>(coords, srcI, dstI, rbfp);

  node_kernel<<<(NN+63)/64, 256, 0, stream>>>(coords, node_W1, node_b1, nodeW2p, node_b2, h, hbf);

  for (int l=0; l<NL; l++){
    hipMemsetAsync(agg, 0, (size_t)NN*DH*4, stream);
    msg_kernel<<<NE/64, 256, 0, stream>>>(hbf, rbfp, srcI, dstI,
        msgW1p + (size_t)l*288*DH, msg_b1 + l*DH,
        msgW2p + (size_t)l*DH*DH, msg_b2 + l*DH, agg);
    upd_kernel<<<(NN+63)/64, 256, 0, stream>>>(hbf, agg,
        updW1p + (size_t)l*256*DH, upd_b1 + l*DH,
        updW2p + (size_t)l*DH*DH, upd_b2 + l*DH, h, hbf);
  }

  head_kernel<<<(NP+63)/64, 256, 0, stream>>>(hbf, coords, pairs,
      headW1p, head_b1, head_W2, head_b2, (float*)d_out);
}